// Round 2
// baseline (265.496 us; speedup 1.0000x reference)
//
#include <hip/hip_runtime.h>

#define INPUT  28
#define HIDDEN 64
#define NOUT   10
#define BLK    256
#define BPB    128   // batches per block (2 threads cooperate per batch)

// out[b,:] = fc_w @ tanh(w_ih @ x[b,27,:] + b_ih + b_hh) + fc_b
// hx == 0 so the w_hh term vanishes; only row 27 of each image is read.
//
// Layout: block handles BPB batches. Threads 0..127 (waves 0,1) = half 0
// (h = 0..31), threads 128..255 (waves 2,3) = half 1 (h = 32..63). The
// half index is wave-uniform, so all weight/bias indices stay wave-uniform
// -> compiler emits s_load (SGPR broadcast), no LDS reads in the hot loop.
__global__ __launch_bounds__(BLK) void rnn_fused2(
    const float* __restrict__ x,
    const float* __restrict__ w_ih,
    const float* __restrict__ b_ih,
    const float* __restrict__ b_hh,
    const float* __restrict__ fc_w,
    const float* __restrict__ fc_b,
    float* __restrict__ out,
    int B)
{
    __shared__ float s_red[BPB][NOUT];   // half-1 partials, 5 KiB

    const int t    = threadIdx.x;
    const int bl   = t & (BPB - 1);
    const int half = t >> 7;             // wave-uniform (waves 0,1 -> 0; 2,3 -> 1)
    const int b    = blockIdx.x * BPB + bl;

    // x[b, 27, 0:28] — 7 aligned float4s (756 and 784 are multiples of 4)
    float inp[INPUT];
    const float4* xp = reinterpret_cast<const float4*>(x + (size_t)b * 784 + 756);
    #pragma unroll
    for (int k = 0; k < 7; ++k) {
        float4 v = xp[k];
        inp[4*k+0] = v.x; inp[4*k+1] = v.y; inp[4*k+2] = v.z; inp[4*k+3] = v.w;
    }

    float acc[NOUT];
    #pragma unroll
    for (int o = 0; o < NOUT; ++o) acc[o] = 0.0f;

    const int h0 = half * (HIDDEN / 2);
    #pragma unroll 2                      // bound SGPR pressure (~40 scalars/iter)
    for (int hh = 0; hh < HIDDEN / 2; ++hh) {
        const int h = h0 + hh;
        float s = b_ih[h] + b_hh[h];                      // uniform -> s_load
        const float* wr = w_ih + h * INPUT;
        #pragma unroll
        for (int c = 0; c < INPUT; ++c)
            s = fmaf(wr[c], inp[c], s);                   // v_fma with SGPR weight

        // fast tanh: 1 - 2/(e^{2s}+1); exact at +/-inf, ~1e-6 abs error
        float e  = __expf(2.0f * s);
        float th = 1.0f - 2.0f / (e + 1.0f);

        #pragma unroll
        for (int o = 0; o < NOUT; ++o)
            acc[o] = fmaf(fc_w[o * HIDDEN + h], th, acc[o]);  // uniform -> s_load
    }

    if (half == 1) {
        #pragma unroll
        for (int o = 0; o < NOUT; ++o) s_red[bl][o] = acc[o];
    }
    __syncthreads();
    if (half == 0) {
        float* op = out + (size_t)b * NOUT;   // 40 B/thread, wave-contiguous
        #pragma unroll
        for (int o = 0; o < NOUT; ++o)
            op[o] = acc[o] + s_red[bl][o] + fc_b[o];
    }
}

extern "C" void kernel_launch(void* const* d_in, const int* in_sizes, int n_in,
                              void* d_out, int out_size, void* d_ws, size_t ws_size,
                              hipStream_t stream)
{
    const float* x    = (const float*)d_in[0];
    const float* w_ih = (const float*)d_in[1];
    // d_in[2] = w_hh — mathematically dead (hx == 0)
    const float* b_ih = (const float*)d_in[3];
    const float* b_hh = (const float*)d_in[4];
    const float* fc_w = (const float*)d_in[5];
    const float* fc_b = (const float*)d_in[6];
    float* out = (float*)d_out;

    const int B = in_sizes[0] / (28 * 28);
    const int grid = (B + BPB - 1) / BPB;   // 512 blocks -> 2048 waves = 2/SIMD
    rnn_fused2<<<grid, BLK, 0, stream>>>(x, w_ih, b_ih, b_hh, fc_w, fc_b, out, B);
}